// Round 9
// baseline (617.933 us; speedup 1.0000x reference)
//
#include <hip/hip_runtime.h>

#define NS 16
#define N_ATOMS 2000
#define NB 2000
#define NA 4000
#define NV 400000
#define NT 6000
#define NI 1000

#define OUT_S 819001
#define OFF_EB 0
#define OFF_EA 2000
#define OFF_EUB 6000
#define OFF_EV 6001
#define OFF_EC 406001
#define OFF_ET 806001
#define OFF_EI 812001
#define OFF_F 813001

#define CHARGE_TENTH 1.8222615f

#define NBF 44000          // bonded force slots: 2000*2 + 4000*3 + 6000*4 + 1000*4
#define BF_BOND 0
#define BF_ANGLE 4000
#define BF_TORS 16000
#define BF_IMP 40000
#define NENT (NV * 2 + NBF)   // 844000 gather entries
#define NBOND_TOT (NB + NA + NT + NI)

// ---------------------------------------------------------------------------
// K1: zero atom counters + E_ub; per-v vdw/charge params.
__global__ __launch_bounds__(512) void init_kernel(
    const float* __restrict__ v14,
    const float* __restrict__ q14,
    const float* __restrict__ pv,
    const float* __restrict__ pc,
    const int*   __restrict__ nb,
    float4* __restrict__ ws,
    int* __restrict__ cnt,
    float* __restrict__ out)
{
    int idx = blockIdx.x * blockDim.x + threadIdx.x;
    if (idx < N_ATOMS) cnt[idx] = 0;
    if (idx < NS) out[(size_t)idx * OUT_S + OFF_EUB] = 0.0f;
    if (idx < NV) {
        int v = idx;
        int i = nb[v];
        int j = nb[NV + v];
        float2 pvi = ((const float2*)pv)[i];
        float2 pvj = ((const float2*)pv)[j];
        float sigma = pvi.x + pvj.x;
        float sig2  = sigma * sigma;
        float sig6  = sig2 * sig2 * sig2;
        float eps   = pvi.y * pvj.y * 0.01f * v14[v];
        float cc    = (CHARGE_TENTH * CHARGE_TENTH) * pc[i] * pc[j] * q14[v];
        float4 w;
        w.x = sig6; w.y = eps; w.z = cc; w.w = 0.0f;
        ws[v] = w;
    }
}

// ---------------------------------------------------------------------------
// K2: histogram contributions per atom (vdw 2/v + bonded).
__global__ __launch_bounds__(256) void hist_kernel(
    const int* __restrict__ nbi,
    const int* __restrict__ bidx,
    const int* __restrict__ aidx,
    const int* __restrict__ tidx,
    const int* __restrict__ iidx,
    int* __restrict__ cnt)
{
    int idx = blockIdx.x * blockDim.x + threadIdx.x;
    if (idx < NV) {
        atomicAdd(&cnt[nbi[2 * idx]], 1);
        atomicAdd(&cnt[nbi[2 * idx + 1]], 1);
    }
    if (idx < NB) {
        atomicAdd(&cnt[bidx[2 * idx]], 1);
        atomicAdd(&cnt[bidx[2 * idx + 1]], 1);
    }
    if (idx < NA) {
        atomicAdd(&cnt[aidx[3 * idx]], 1);
        atomicAdd(&cnt[aidx[3 * idx + 1]], 1);
        atomicAdd(&cnt[aidx[3 * idx + 2]], 1);
    }
    if (idx < NT) {
        #pragma unroll
        for (int p = 0; p < 4; ++p) atomicAdd(&cnt[tidx[4 * idx + p]], 1);
    }
    if (idx < NI) {
        #pragma unroll
        for (int p = 0; p < 4; ++p) atomicAdd(&cnt[iidx[4 * idx + p]], 1);
    }
}

// ---------------------------------------------------------------------------
// K3: exclusive scan of cnt -> startx[0..N_ATOMS], cursor = startx. One wave.
__global__ __launch_bounds__(64) void scan_kernel(
    const int* __restrict__ cnt,
    int* __restrict__ startx,
    int* __restrict__ cursor)
{
    int lane = threadIdx.x;
    const int CH = (N_ATOMS + 63) / 64;   // 32
    int a0 = lane * CH;
    int a1 = a0 + CH; if (a1 > N_ATOMS) a1 = N_ATOMS;
    int tot = 0;
    for (int a = a0; a < a1; ++a) tot += cnt[a];
    // exclusive scan of tot across 64 lanes
    int incl = tot;
    #pragma unroll
    for (int off = 1; off < 64; off <<= 1) {
        int n = __shfl_up(incl, off);
        if (lane >= off) incl += n;
    }
    int run = incl - tot;
    for (int a = a0; a < a1; ++a) {
        startx[a] = run;
        cursor[a] = run;
        run += cnt[a];
    }
    if (lane == 63) startx[N_ATOMS] = run;
}

// ---------------------------------------------------------------------------
// K4: placement — write entry codes into atom-sorted lists.
// vdw entry: e = 2*v + end (< 2^20). bonded entry: 0x80000000 | bf_slot.
__global__ __launch_bounds__(256) void place_kernel(
    const int* __restrict__ nbi,
    const int* __restrict__ bidx,
    const int* __restrict__ aidx,
    const int* __restrict__ tidx,
    const int* __restrict__ iidx,
    int* __restrict__ cursor,
    unsigned* __restrict__ entries)
{
    int idx = blockIdx.x * blockDim.x + threadIdx.x;
    if (idx < NV) {
        int p0 = atomicAdd(&cursor[nbi[2 * idx]], 1);
        entries[p0] = (unsigned)(2 * idx);
        int p1 = atomicAdd(&cursor[nbi[2 * idx + 1]], 1);
        entries[p1] = (unsigned)(2 * idx + 1);
    }
    if (idx < NB) {
        #pragma unroll
        for (int sl = 0; sl < 2; ++sl) {
            int p = atomicAdd(&cursor[bidx[2 * idx + sl]], 1);
            entries[p] = 0x80000000u | (unsigned)(BF_BOND + idx * 2 + sl);
        }
    }
    if (idx < NA) {
        #pragma unroll
        for (int sl = 0; sl < 3; ++sl) {
            int p = atomicAdd(&cursor[aidx[3 * idx + sl]], 1);
            entries[p] = 0x80000000u | (unsigned)(BF_ANGLE + idx * 3 + sl);
        }
    }
    if (idx < NT) {
        #pragma unroll
        for (int sl = 0; sl < 4; ++sl) {
            int p = atomicAdd(&cursor[tidx[4 * idx + sl]], 1);
            entries[p] = 0x80000000u | (unsigned)(BF_TORS + idx * 4 + sl);
        }
    }
    if (idx < NI) {
        #pragma unroll
        for (int sl = 0; sl < 4; ++sl) {
            int p = atomicAdd(&cursor[iidx[4 * idx + sl]], 1);
            entries[p] = 0x80000000u | (unsigned)(BF_IMP + idx * 4 + sl);
        }
    }
}

// ---------------------------------------------------------------------------
// K5: streaming — vdw/charge energies + per-v force scalar fs.
__global__ __launch_bounds__(256) void stream_kernel(
    const float*  __restrict__ lv,
    const float4* __restrict__ ws,
    float* __restrict__ fs,
    float* __restrict__ out)
{
    int v = blockIdx.x * 256 + threadIdx.x;
    int s = blockIdx.y;
    if (v >= NV) return;
    float4 w = ws[v];
    float r = lv[(size_t)s * NV + v];
    float rinv  = __builtin_amdgcn_rcpf(r);
    float r2inv = rinv * rinv;
    float r6inv = r2inv * r2inv * r2inv;
    float t     = w.x * r6inv;
    float eps   = w.y;
    float cc    = w.z;
    float* outE = out + (size_t)s * OUT_S;
    outE[OFF_EV + v] = eps * (t * t - 2.0f * t);
    outE[OFF_EC + v] = cc * rinv;
    fs[(size_t)s * NV + v] = 12.0f * eps * t * (1.0f - t) * rinv - cc * r2inv;
}

// ---------------------------------------------------------------------------
// K6: bonded pre-pass — energies + explicit per-slot force triples bf.
__global__ __launch_bounds__(256) void bonded_kernel(
    const float* __restrict__ lb,
    const float* __restrict__ th,
    const float* __restrict__ sc,
    const float* __restrict__ c2i,
    const float* __restrict__ pb,
    const float* __restrict__ pa,
    const float* __restrict__ pt,
    const float* __restrict__ pim,
    const float* __restrict__ dlb,
    const float* __restrict__ dth,
    const float* __restrict__ dtt,
    const float* __restrict__ dc2,
    float* __restrict__ bf,
    float* __restrict__ out)
{
    int t = blockIdx.x * 256 + threadIdx.x;
    int s = blockIdx.y;
    if (t >= NBOND_TOT) return;
    float* outE = out + (size_t)s * OUT_S;
    float* bfrow = bf + (size_t)s * NBF * 3;

    if (t < NB) {
        int b = t;
        float2 p = ((const float2*)pb)[b];
        float K  = p.x * 100.0f;
        float d  = lb[s * NB + b] - p.y;
        outE[OFF_EB + b] = K * d * d;
        float g = 2.0f * K * d;
        const float* dd = dlb + ((size_t)s * NB + b) * 6;
        float* o = bfrow + (size_t)(BF_BOND + b * 2) * 3;
        #pragma unroll
        for (int c = 0; c < 6; ++c) o[c] = dd[c] * g;
    } else if (t < NB + NA) {
        int a = t - NB;
        float2 p = ((const float2*)pa)[a];
        float Ka  = p.x * 10.0f;
        float da  = th[s * NA + a] - p.y * 0.31415926535f;
        outE[OFF_EA + a] = Ka * da * da;
        float g = 2.0f * Ka * da;
        const float* dd = dth + ((size_t)s * NA + a) * 9;
        float* o = bfrow + (size_t)(BF_ANGLE + a * 3) * 3;
        #pragma unroll
        for (int c = 0; c < 9; ++c) o[c] = dd[c] * g;
    } else if (t < NB + NA + NT) {
        int tt = t - (NB + NA);
        const float4* s8 = (const float4*)(sc + ((size_t)s * NT + tt) * 8);
        float4 sA = s8[0], sB = s8[1];
        float4 p4 = ((const float4*)pt)[tt];
        float E  = sA.y * p4.x + sA.w * p4.y + sB.y * p4.z + sB.w * p4.w;
        float Sf = sA.x * p4.x + sA.z * p4.y * 2.0f + sB.x * p4.z * 3.0f + sB.z * p4.w * 4.0f;
        outE[OFF_ET + tt] = E;
        float g = -Sf;
        const float* dd = dtt + ((size_t)s * NT + tt) * 12;
        float* o = bfrow + (size_t)(BF_TORS + tt * 4) * 3;
        #pragma unroll
        for (int c = 0; c < 12; ++c) o[c] = dd[c] * g;
    } else {
        int ii = t - (NB + NA + NT);
        float ki = pim[ii];
        outE[OFF_EI + ii] = ki * (1.0f - c2i[s * NI + ii]);
        float g = -ki;
        const float* dd = dc2 + ((size_t)s * NI + ii) * 12;
        float* o = bfrow + (size_t)(BF_IMP + ii * 4) * 3;
        #pragma unroll
        for (int c = 0; c < 12; ++c) o[c] = dd[c] * g;
    }
}

// ---------------------------------------------------------------------------
// K7: gather — one wave per (s, atom). Plain scattered loads, register
// accumulate, wave-reduce, single plain store. Zero atomics.
__global__ __launch_bounds__(256, 4) void gather_kernel(
    const unsigned* __restrict__ entries,
    const int* __restrict__ startx,
    const float* __restrict__ fs,
    const float* __restrict__ dlv,
    const float* __restrict__ bf,
    float* __restrict__ out)
{
    int wid  = blockIdx.x * 4 + (threadIdx.x >> 6);   // 0..31999
    int lane = threadIdx.x & 63;
    int s = wid / N_ATOMS;
    int a = wid - s * N_ATOMS;

    const float* fsrow = fs  + (size_t)s * NV;
    const float* drow  = dlv + (size_t)s * NV * 6;
    const float* bfrow = bf  + (size_t)s * NBF * 3;

    int base = startx[a];
    int endp = startx[a + 1];

    float ax = 0.0f, ay = 0.0f, az = 0.0f;
    for (int i = base + lane; i < endp; i += 64) {
        unsigned e = entries[i];
        if (e & 0x80000000u) {
            const float* b = bfrow + (size_t)(e & 0x7fffffffu) * 3;
            ax += b[0]; ay += b[1]; az += b[2];
        } else {
            float f = fsrow[e >> 1];
            const float* d = drow + (size_t)e * 3;
            ax += f * d[0]; ay += f * d[1]; az += f * d[2];
        }
    }

    #pragma unroll
    for (int off = 32; off > 0; off >>= 1) {
        ax += __shfl_down(ax, off);
        ay += __shfl_down(ay, off);
        az += __shfl_down(az, off);
    }
    if (lane == 0) {
        float* F = out + (size_t)s * OUT_S + OFF_F + 3 * a;
        F[0] = ax; F[1] = ay; F[2] = az;
    }
}

// ---------------------------------------------------------------------------
extern "C" void kernel_launch(void* const* d_in, const int* in_sizes, int n_in,
                              void* d_out, int out_size, void* d_ws, size_t ws_size,
                              hipStream_t stream) {
    const float* lb  = (const float*)d_in[0];
    const float* th  = (const float*)d_in[1];
    const float* lv  = (const float*)d_in[2];
    const float* sc  = (const float*)d_in[3];
    const float* c2i = (const float*)d_in[4];
    const float* v14 = (const float*)d_in[5];
    const float* q14 = (const float*)d_in[6];
    const float* pb  = (const float*)d_in[7];
    const float* pa  = (const float*)d_in[8];
    const float* pv  = (const float*)d_in[9];
    const float* pc  = (const float*)d_in[10];
    const float* pt  = (const float*)d_in[11];
    const float* pim = (const float*)d_in[12];
    const float* dlb = (const float*)d_in[13];
    const float* dth = (const float*)d_in[14];
    const float* dlv = (const float*)d_in[15];
    const float* dtt = (const float*)d_in[16];
    const float* dc2 = (const float*)d_in[17];
    const int* nb    = (const int*)d_in[18];
    const int* bidx  = (const int*)d_in[19];
    const int* aidx  = (const int*)d_in[20];
    const int* nbi   = (const int*)d_in[21];
    const int* tidx  = (const int*)d_in[22];
    const int* iidx  = (const int*)d_in[23];
    float* out = (float*)d_out;

    // ws layout (floats): ws params | fs | bf | entries | cnt | startx | cursor
    float*    wsf     = (float*)d_ws;
    float4*   ws      = (float4*)wsf;                       // NV float4
    float*    fs      = wsf + (size_t)NV * 4;               // NS*NV
    float*    bf      = fs + (size_t)NS * NV;               // NS*NBF*3
    unsigned* entries = (unsigned*)(bf + (size_t)NS * NBF * 3);  // NENT
    int*      cnt     = (int*)(entries + NENT);             // N_ATOMS
    int*      startx  = cnt + N_ATOMS;                      // N_ATOMS+1
    int*      cursor  = startx + N_ATOMS + 1;               // N_ATOMS

    // K1: params + zero counters + E_ub
    init_kernel<<<(NV + 511) / 512, 512, 0, stream>>>(v14, q14, pv, pc, nb, ws, cnt, out);
    // K2: histogram
    hist_kernel<<<(NV + 255) / 256, 256, 0, stream>>>(nbi, bidx, aidx, tidx, iidx, cnt);
    // K3: scan
    scan_kernel<<<1, 64, 0, stream>>>(cnt, startx, cursor);
    // K4: placement
    place_kernel<<<(NV + 255) / 256, 256, 0, stream>>>(nbi, bidx, aidx, tidx, iidx, cursor, entries);
    // K5: stream energies + fs
    {
        dim3 grid((NV + 255) / 256, NS);
        stream_kernel<<<grid, 256, 0, stream>>>(lv, ws, fs, out);
    }
    // K6: bonded energies + force triples
    {
        dim3 grid((NBOND_TOT + 255) / 256, NS);
        bonded_kernel<<<grid, 256, 0, stream>>>(lb, th, sc, c2i, pb, pa, pt, pim,
                                                dlb, dth, dtt, dc2, bf, out);
    }
    // K7: gather forces
    {
        gather_kernel<<<NS * N_ATOMS / 4, 256, 0, stream>>>(entries, startx, fs, dlv, bf, out);
    }
}

// Round 10
// 394.689 us; speedup vs baseline: 1.5656x; 1.5656x over previous
//
#include <hip/hip_runtime.h>

#define NS 16
#define N_ATOMS 2000
#define NB 2000
#define NA 4000
#define NV 400000
#define NT 6000
#define NI 1000

#define OUT_S 819001
#define OFF_EB 0
#define OFF_EA 2000
#define OFF_EUB 6000
#define OFF_EV 6001
#define OFF_EC 406001
#define OFF_ET 806001
#define OFF_EI 812001
#define OFF_F 813001

#define CHARGE_TENTH 1.8222615f

#define NBF 44000            // bonded force slots
#define BF_BOND 0
#define BF_ANGLE 4000
#define BF_TORS 16000
#define BF_IMP 40000
#define NENT (NV * 2 + NBF)  // 844000
#define NBOND_TOT (NB + NA + NT + NI)   // 13000
#define NITEMS (NV + NB + NA + NT + NI) // 413000
#define NCB 256              // hist/place blocks
#define IPB ((NITEMS + NCB - 1) / NCB)  // 1614
#define SBLK 1563            // stream blocks per sample in fat kernel
#define BBLK ((NBOND_TOT + 255) / 256)  // 51

// ---------------------------------------------------------------------------
// K1: E_ub zero + per-v vdw/charge params.
__global__ __launch_bounds__(512) void init_kernel(
    const float* __restrict__ v14,
    const float* __restrict__ q14,
    const float* __restrict__ pv,
    const float* __restrict__ pc,
    const int*   __restrict__ nb,
    float4* __restrict__ ws,
    float* __restrict__ out)
{
    int idx = blockIdx.x * blockDim.x + threadIdx.x;
    if (idx < NS) out[(size_t)idx * OUT_S + OFF_EUB] = 0.0f;
    if (idx < NV) {
        int v = idx;
        int i = nb[v];
        int j = nb[NV + v];
        float2 pvi = ((const float2*)pv)[i];
        float2 pvj = ((const float2*)pv)[j];
        float sigma = pvi.x + pvj.x;
        float sig2  = sigma * sigma;
        float sig6  = sig2 * sig2 * sig2;
        float eps   = pvi.y * pvj.y * 0.01f * v14[v];
        float cc    = (CHARGE_TENTH * CHARGE_TENTH) * pc[i] * pc[j] * q14[v];
        float4 w;
        w.x = sig6; w.y = eps; w.z = cc; w.w = 0.0f;
        ws[v] = w;
    }
}

// ---------------------------------------------------------------------------
// item t -> (#entries, atoms, codes). Shared by hist & place.
// t<NV: vdw v (2 entries). Then bonds(2), angles(3), torsions(4), imptors(4).

// K2: per-block LDS histogram -> counts[b][a] (plain store, no global atomics)
__global__ __launch_bounds__(256, 4) void hist_kernel(
    const int* __restrict__ nbi,
    const int* __restrict__ bidx,
    const int* __restrict__ aidx,
    const int* __restrict__ tidx,
    const int* __restrict__ iidx,
    int* __restrict__ counts)
{
    __shared__ int h[N_ATOMS];
    int tid = threadIdx.x;
    int b   = blockIdx.x;
    for (int k = tid; k < N_ATOMS; k += 256) h[k] = 0;
    __syncthreads();
    int t0 = b * IPB;
    int t1 = t0 + IPB; if (t1 > NITEMS) t1 = NITEMS;
    for (int t = t0 + tid; t < t1; t += 256) {
        if (t < NV) {
            atomicAdd(&h[nbi[2 * t]], 1);
            atomicAdd(&h[nbi[2 * t + 1]], 1);
        } else if (t < NV + NB) {
            int x = t - NV;
            atomicAdd(&h[bidx[2 * x]], 1);
            atomicAdd(&h[bidx[2 * x + 1]], 1);
        } else if (t < NV + NB + NA) {
            int x = t - (NV + NB);
            atomicAdd(&h[aidx[3 * x]], 1);
            atomicAdd(&h[aidx[3 * x + 1]], 1);
            atomicAdd(&h[aidx[3 * x + 2]], 1);
        } else if (t < NV + NB + NA + NT) {
            int x = t - (NV + NB + NA);
            #pragma unroll
            for (int p = 0; p < 4; ++p) atomicAdd(&h[tidx[4 * x + p]], 1);
        } else {
            int x = t - (NV + NB + NA + NT);
            #pragma unroll
            for (int p = 0; p < 4; ++p) atomicAdd(&h[iidx[4 * x + p]], 1);
        }
    }
    __syncthreads();
    for (int k = tid; k < N_ATOMS; k += 256) counts[(size_t)b * N_ATOMS + k] = h[k];
}

// K3a: column scan — counts[b][a] becomes exclusive prefix over b; total[a].
__global__ __launch_bounds__(256) void colscan_kernel(
    int* __restrict__ counts,
    int* __restrict__ total)
{
    int a = blockIdx.x * 256 + threadIdx.x;
    if (a >= N_ATOMS) return;
    int pre = 0;
    for (int b = 0; b < NCB; ++b) {
        int c = counts[(size_t)b * N_ATOMS + a];
        counts[(size_t)b * N_ATOMS + a] = pre;
        pre += c;
    }
    total[a] = pre;
}

// K3b: single-wave exclusive scan over atoms -> startx[0..N_ATOMS].
__global__ __launch_bounds__(64) void scan_kernel(
    const int* __restrict__ total,
    int* __restrict__ startx)
{
    int lane = threadIdx.x;
    const int CH = (N_ATOMS + 63) / 64;
    int a0 = lane * CH;
    int a1 = a0 + CH; if (a1 > N_ATOMS) a1 = N_ATOMS;
    int tot = 0;
    for (int a = a0; a < a1; ++a) tot += total[a];
    int incl = tot;
    #pragma unroll
    for (int off = 1; off < 64; off <<= 1) {
        int n = __shfl_up(incl, off);
        if (lane >= off) incl += n;
    }
    int run = incl - tot;
    for (int a = a0; a < a1; ++a) {
        startx[a] = run;
        run += total[a];
    }
    if (lane == 63) startx[N_ATOMS] = run;
}

// K4: placement with LDS cursors seeded from startx + per-block prefix.
__global__ __launch_bounds__(256, 4) void place_kernel(
    const int* __restrict__ nbi,
    const int* __restrict__ bidx,
    const int* __restrict__ aidx,
    const int* __restrict__ tidx,
    const int* __restrict__ iidx,
    const int* __restrict__ counts,   // exclusive per-block prefix
    const int* __restrict__ startx,
    unsigned* __restrict__ entries)
{
    __shared__ int cur[N_ATOMS];
    int tid = threadIdx.x;
    int b   = blockIdx.x;
    for (int k = tid; k < N_ATOMS; k += 256)
        cur[k] = startx[k] + counts[(size_t)b * N_ATOMS + k];
    __syncthreads();
    int t0 = b * IPB;
    int t1 = t0 + IPB; if (t1 > NITEMS) t1 = NITEMS;
    for (int t = t0 + tid; t < t1; t += 256) {
        if (t < NV) {
            int p0 = atomicAdd(&cur[nbi[2 * t]], 1);
            entries[p0] = (unsigned)(2 * t);
            int p1 = atomicAdd(&cur[nbi[2 * t + 1]], 1);
            entries[p1] = (unsigned)(2 * t + 1);
        } else if (t < NV + NB) {
            int x = t - NV;
            #pragma unroll
            for (int sl = 0; sl < 2; ++sl) {
                int p = atomicAdd(&cur[bidx[2 * x + sl]], 1);
                entries[p] = 0x80000000u | (unsigned)(BF_BOND + x * 2 + sl);
            }
        } else if (t < NV + NB + NA) {
            int x = t - (NV + NB);
            #pragma unroll
            for (int sl = 0; sl < 3; ++sl) {
                int p = atomicAdd(&cur[aidx[3 * x + sl]], 1);
                entries[p] = 0x80000000u | (unsigned)(BF_ANGLE + x * 3 + sl);
            }
        } else if (t < NV + NB + NA + NT) {
            int x = t - (NV + NB + NA);
            #pragma unroll
            for (int sl = 0; sl < 4; ++sl) {
                int p = atomicAdd(&cur[tidx[4 * x + sl]], 1);
                entries[p] = 0x80000000u | (unsigned)(BF_TORS + x * 4 + sl);
            }
        } else {
            int x = t - (NV + NB + NA + NT);
            #pragma unroll
            for (int sl = 0; sl < 4; ++sl) {
                int p = atomicAdd(&cur[iidx[4 * x + sl]], 1);
                entries[p] = 0x80000000u | (unsigned)(BF_IMP + x * 4 + sl);
            }
        }
    }
}

// ---------------------------------------------------------------------------
// K5: fat kernel — stream (x < SBLK) and bonded pre-pass (x >= SBLK).
__global__ __launch_bounds__(256, 4) void work_kernel(
    const float*  __restrict__ lv,
    const float4* __restrict__ ws,
    const float* __restrict__ lb,
    const float* __restrict__ th,
    const float* __restrict__ sc,
    const float* __restrict__ c2i,
    const float* __restrict__ pb,
    const float* __restrict__ pa,
    const float* __restrict__ pt,
    const float* __restrict__ pim,
    const float* __restrict__ dlb,
    const float* __restrict__ dth,
    const float* __restrict__ dtt,
    const float* __restrict__ dc2,
    float* __restrict__ fs,
    float* __restrict__ bf,
    float* __restrict__ out)
{
    int x = blockIdx.x;
    int s = blockIdx.y;
    int tid = threadIdx.x;
    float* outE = out + (size_t)s * OUT_S;

    if (x < SBLK) {
        int v = x * 256 + tid;
        if (v >= NV) return;
        float4 w = ws[v];
        float r = lv[(size_t)s * NV + v];
        float rinv  = __builtin_amdgcn_rcpf(r);
        float r2inv = rinv * rinv;
        float r6inv = r2inv * r2inv * r2inv;
        float t     = w.x * r6inv;
        float eps   = w.y;
        float cc    = w.z;
        outE[OFF_EV + v] = eps * (t * t - 2.0f * t);
        outE[OFF_EC + v] = cc * rinv;
        fs[(size_t)s * NV + v] = 12.0f * eps * t * (1.0f - t) * rinv - cc * r2inv;
        return;
    }

    int t = (x - SBLK) * 256 + tid;
    if (t >= NBOND_TOT) return;
    float* bfrow = bf + (size_t)s * NBF * 3;

    if (t < NB) {
        int b = t;
        float2 p = ((const float2*)pb)[b];
        float K  = p.x * 100.0f;
        float d  = lb[s * NB + b] - p.y;
        outE[OFF_EB + b] = K * d * d;
        float g = 2.0f * K * d;
        const float* dd = dlb + ((size_t)s * NB + b) * 6;
        float* o = bfrow + (size_t)(BF_BOND + b * 2) * 3;
        #pragma unroll
        for (int c = 0; c < 6; ++c) o[c] = dd[c] * g;
    } else if (t < NB + NA) {
        int a = t - NB;
        float2 p = ((const float2*)pa)[a];
        float Ka  = p.x * 10.0f;
        float da  = th[s * NA + a] - p.y * 0.31415926535f;
        outE[OFF_EA + a] = Ka * da * da;
        float g = 2.0f * Ka * da;
        const float* dd = dth + ((size_t)s * NA + a) * 9;
        float* o = bfrow + (size_t)(BF_ANGLE + a * 3) * 3;
        #pragma unroll
        for (int c = 0; c < 9; ++c) o[c] = dd[c] * g;
    } else if (t < NB + NA + NT) {
        int tt = t - (NB + NA);
        const float4* s8 = (const float4*)(sc + ((size_t)s * NT + tt) * 8);
        float4 sA = s8[0], sB = s8[1];
        float4 p4 = ((const float4*)pt)[tt];
        float E  = sA.y * p4.x + sA.w * p4.y + sB.y * p4.z + sB.w * p4.w;
        float Sf = sA.x * p4.x + sA.z * p4.y * 2.0f + sB.x * p4.z * 3.0f + sB.z * p4.w * 4.0f;
        outE[OFF_ET + tt] = E;
        float g = -Sf;
        const float* dd = dtt + ((size_t)s * NT + tt) * 12;
        float* o = bfrow + (size_t)(BF_TORS + tt * 4) * 3;
        #pragma unroll
        for (int c = 0; c < 12; ++c) o[c] = dd[c] * g;
    } else {
        int ii = t - (NB + NA + NT);
        float ki = pim[ii];
        outE[OFF_EI + ii] = ki * (1.0f - c2i[s * NI + ii]);
        float g = -ki;
        const float* dd = dc2 + ((size_t)s * NI + ii) * 12;
        float* o = bfrow + (size_t)(BF_IMP + ii * 4) * 3;
        #pragma unroll
        for (int c = 0; c < 12; ++c) o[c] = dd[c] * g;
    }
}

// ---------------------------------------------------------------------------
// K6: gather — one wave per (s,atom), XCD-locality swizzle: all blocks of
// sample s have blockIdx % 8 == s % 8 (round-robin XCD heuristic) so the
// sample's dlv/fs stream window stays in ONE XCD's L2.
__global__ __launch_bounds__(256, 8) void gather_kernel(
    const unsigned* __restrict__ entries,
    const int* __restrict__ startx,
    const float* __restrict__ fs,
    const float* __restrict__ dlv,
    const float* __restrict__ bf,
    float* __restrict__ out)
{
    unsigned B = blockIdx.x;
    int xcd = B & 7;
    int rnd = B >> 3;              // 0..999
    int s   = ((rnd & 1) << 3) | xcd;
    int j   = rnd >> 1;            // 0..499
    int a   = j * 4 + (threadIdx.x >> 6);
    int lane = threadIdx.x & 63;

    const float* fsrow = fs  + (size_t)s * NV;
    const float* drow  = dlv + (size_t)s * NV * 6;
    const float* bfrow = bf  + (size_t)s * NBF * 3;

    int base = startx[a];
    int endp = startx[a + 1];

    float ax = 0.0f, ay = 0.0f, az = 0.0f;
    for (int i = base + lane; i < endp; i += 64) {
        unsigned e = entries[i];
        if (e & 0x80000000u) {
            const float* b = bfrow + (size_t)(e & 0x7fffffffu) * 3;
            ax += b[0]; ay += b[1]; az += b[2];
        } else {
            float f = fsrow[e >> 1];
            const float* d = drow + (size_t)e * 3;
            ax += f * d[0]; ay += f * d[1]; az += f * d[2];
        }
    }

    #pragma unroll
    for (int off = 32; off > 0; off >>= 1) {
        ax += __shfl_down(ax, off);
        ay += __shfl_down(ay, off);
        az += __shfl_down(az, off);
    }
    if (lane == 0) {
        float* F = out + (size_t)s * OUT_S + OFF_F + 3 * a;
        F[0] = ax; F[1] = ay; F[2] = az;
    }
}

// ---------------------------------------------------------------------------
extern "C" void kernel_launch(void* const* d_in, const int* in_sizes, int n_in,
                              void* d_out, int out_size, void* d_ws, size_t ws_size,
                              hipStream_t stream) {
    const float* lb  = (const float*)d_in[0];
    const float* th  = (const float*)d_in[1];
    const float* lv  = (const float*)d_in[2];
    const float* sc  = (const float*)d_in[3];
    const float* c2i = (const float*)d_in[4];
    const float* v14 = (const float*)d_in[5];
    const float* q14 = (const float*)d_in[6];
    const float* pb  = (const float*)d_in[7];
    const float* pa  = (const float*)d_in[8];
    const float* pv  = (const float*)d_in[9];
    const float* pc  = (const float*)d_in[10];
    const float* pt  = (const float*)d_in[11];
    const float* pim = (const float*)d_in[12];
    const float* dlb = (const float*)d_in[13];
    const float* dth = (const float*)d_in[14];
    const float* dlv = (const float*)d_in[15];
    const float* dtt = (const float*)d_in[16];
    const float* dc2 = (const float*)d_in[17];
    const int* nb    = (const int*)d_in[18];
    const int* bidx  = (const int*)d_in[19];
    const int* aidx  = (const int*)d_in[20];
    const int* nbi   = (const int*)d_in[21];
    const int* tidx  = (const int*)d_in[22];
    const int* iidx  = (const int*)d_in[23];
    float* out = (float*)d_out;

    // ws layout (floats): params | fs | bf | entries | counts | total | startx
    float*    wsf     = (float*)d_ws;
    float4*   ws      = (float4*)wsf;                            // NV f4
    float*    fs      = wsf + (size_t)NV * 4;                    // NS*NV
    float*    bf      = fs + (size_t)NS * NV;                    // NS*NBF*3
    unsigned* entries = (unsigned*)(bf + (size_t)NS * NBF * 3);  // NENT
    int*      counts  = (int*)(entries + NENT);                  // NCB*N_ATOMS
    int*      total   = counts + (size_t)NCB * N_ATOMS;          // N_ATOMS
    int*      startx  = total + N_ATOMS;                         // N_ATOMS+1

    init_kernel<<<(NV + 511) / 512, 512, 0, stream>>>(v14, q14, pv, pc, nb, ws, out);
    hist_kernel<<<NCB, 256, 0, stream>>>(nbi, bidx, aidx, tidx, iidx, counts);
    colscan_kernel<<<(N_ATOMS + 255) / 256, 256, 0, stream>>>(counts, total);
    scan_kernel<<<1, 64, 0, stream>>>(total, startx);
    place_kernel<<<NCB, 256, 0, stream>>>(nbi, bidx, aidx, tidx, iidx, counts, startx, entries);
    {
        dim3 grid(SBLK + BBLK, NS);
        work_kernel<<<grid, 256, 0, stream>>>(lv, ws, lb, th, sc, c2i, pb, pa, pt, pim,
                                              dlb, dth, dtt, dc2, fs, bf, out);
    }
    gather_kernel<<<8000, 256, 0, stream>>>(entries, startx, fs, dlv, bf, out);
}

// Round 11
// 172.561 us; speedup vs baseline: 3.5810x; 2.2872x over previous
//
#include <hip/hip_runtime.h>
#include <hip/hip_fp16.h>

#define NS 16
#define N_ATOMS 2000
#define NB 2000
#define NA 4000
#define NV 400000
#define NT 6000
#define NI 1000

#define OUT_S 819001
#define OFF_EB 0
#define OFF_EA 2000
#define OFF_EUB 6000
#define OFF_EV 6001
#define OFF_EC 406001
#define OFF_ET 806001
#define OFF_EI 812001
#define OFF_F 813001

#define CHARGE_TENTH 1.8222615f

#define NBF 44000            // bonded slots: 2000*2 + 4000*3 + 6000*4 + 1000*4
#define BF_BOND 0
#define BF_ANGLE 4000
#define BF_TORS 16000
#define BF_IMP 40000
#define NENT (NV * 2 + NBF)  // 844000 entries (atom-sorted contribution slots)
#define NBOND_TOT (NB + NA + NT + NI)   // 13000
#define NITEMS (NV + NB + NA + NT + NI) // 413000
#define NCB 256
#define IPB ((NITEMS + NCB - 1) / NCB)  // 1614

typedef __fp16 hv2 __attribute__((ext_vector_type(2)));

__device__ __forceinline__ unsigned pkrtz(float a, float b) {
    hv2 h = __builtin_amdgcn_cvt_pkrtz(a, b);
    return __builtin_bit_cast(unsigned, h);
}
__device__ __forceinline__ unsigned hadd2u(unsigned x, unsigned y) {
    __half2 a = __builtin_bit_cast(__half2, x);
    __half2 b = __builtin_bit_cast(__half2, y);
    return __builtin_bit_cast(unsigned, __hadd2(a, b));
}

// ---------------------------------------------------------------------------
// K1: E_ub zero + per-v vdw/charge params.
__global__ __launch_bounds__(512) void init_kernel(
    const float* __restrict__ v14, const float* __restrict__ q14,
    const float* __restrict__ pv, const float* __restrict__ pc,
    const int* __restrict__ nb, float4* __restrict__ ws, float* __restrict__ out)
{
    int idx = blockIdx.x * blockDim.x + threadIdx.x;
    if (idx < NS) out[(size_t)idx * OUT_S + OFF_EUB] = 0.0f;
    if (idx < NV) {
        int v = idx;
        int i = nb[v];
        int j = nb[NV + v];
        float2 pvi = ((const float2*)pv)[i];
        float2 pvj = ((const float2*)pv)[j];
        float sigma = pvi.x + pvj.x;
        float sig2 = sigma * sigma;
        float4 w;
        w.x = sig2 * sig2 * sig2;
        w.y = pvi.y * pvj.y * 0.01f * v14[v];
        w.z = (CHARGE_TENTH * CHARGE_TENTH) * pc[i] * pc[j] * q14[v];
        w.w = 0.0f;
        ws[v] = w;
    }
}

// ---------------------------------------------------------------------------
// K2: per-block LDS histogram of contributions per atom.
__global__ __launch_bounds__(256, 4) void hist_kernel(
    const int* __restrict__ nbi, const int* __restrict__ bidx,
    const int* __restrict__ aidx, const int* __restrict__ tidx,
    const int* __restrict__ iidx, int* __restrict__ counts)
{
    __shared__ int h[N_ATOMS];
    int tid = threadIdx.x, b = blockIdx.x;
    for (int k = tid; k < N_ATOMS; k += 256) h[k] = 0;
    __syncthreads();
    int t0 = b * IPB, t1 = t0 + IPB; if (t1 > NITEMS) t1 = NITEMS;
    for (int t = t0 + tid; t < t1; t += 256) {
        if (t < NV) {
            atomicAdd(&h[nbi[2 * t]], 1);
            atomicAdd(&h[nbi[2 * t + 1]], 1);
        } else if (t < NV + NB) {
            int x = t - NV;
            atomicAdd(&h[bidx[2 * x]], 1);
            atomicAdd(&h[bidx[2 * x + 1]], 1);
        } else if (t < NV + NB + NA) {
            int x = t - (NV + NB);
            atomicAdd(&h[aidx[3 * x]], 1);
            atomicAdd(&h[aidx[3 * x + 1]], 1);
            atomicAdd(&h[aidx[3 * x + 2]], 1);
        } else if (t < NV + NB + NA + NT) {
            int x = t - (NV + NB + NA);
            #pragma unroll
            for (int p = 0; p < 4; ++p) atomicAdd(&h[tidx[4 * x + p]], 1);
        } else {
            int x = t - (NV + NB + NA + NT);
            #pragma unroll
            for (int p = 0; p < 4; ++p) atomicAdd(&h[iidx[4 * x + p]], 1);
        }
    }
    __syncthreads();
    for (int k = tid; k < N_ATOMS; k += 256) counts[(size_t)b * N_ATOMS + k] = h[k];
}

// K3a: column scan over blocks.
__global__ __launch_bounds__(256) void colscan_kernel(
    int* __restrict__ counts, int* __restrict__ total)
{
    int a = blockIdx.x * 256 + threadIdx.x;
    if (a >= N_ATOMS) return;
    int pre = 0;
    for (int b = 0; b < NCB; ++b) {
        int c = counts[(size_t)b * N_ATOMS + a];
        counts[(size_t)b * N_ATOMS + a] = pre;
        pre += c;
    }
    total[a] = pre;
}

// K3b: single-wave exclusive scan over atoms.
__global__ __launch_bounds__(64) void scan_kernel(
    const int* __restrict__ total, int* __restrict__ startx)
{
    int lane = threadIdx.x;
    const int CH = (N_ATOMS + 63) / 64;
    int a0 = lane * CH, a1 = a0 + CH; if (a1 > N_ATOMS) a1 = N_ATOMS;
    int tot = 0;
    for (int a = a0; a < a1; ++a) tot += total[a];
    int incl = tot;
    #pragma unroll
    for (int off = 1; off < 64; off <<= 1) {
        int n = __shfl_up(incl, off);
        if (lane >= off) incl += n;
    }
    int run = incl - tot;
    for (int a = a0; a < a1; ++a) { startx[a] = run; run += total[a]; }
    if (lane == 63) startx[N_ATOMS] = run;
}

// K4: placement — write INVERSE permutation pos[code] = slot.
__global__ __launch_bounds__(256, 4) void place_kernel(
    const int* __restrict__ nbi, const int* __restrict__ bidx,
    const int* __restrict__ aidx, const int* __restrict__ tidx,
    const int* __restrict__ iidx, const int* __restrict__ counts,
    const int* __restrict__ startx,
    int* __restrict__ posv, int* __restrict__ posb)
{
    __shared__ int cur[N_ATOMS];
    int tid = threadIdx.x, b = blockIdx.x;
    for (int k = tid; k < N_ATOMS; k += 256)
        cur[k] = startx[k] + counts[(size_t)b * N_ATOMS + k];
    __syncthreads();
    int t0 = b * IPB, t1 = t0 + IPB; if (t1 > NITEMS) t1 = NITEMS;
    for (int t = t0 + tid; t < t1; t += 256) {
        if (t < NV) {
            posv[2 * t]     = atomicAdd(&cur[nbi[2 * t]], 1);
            posv[2 * t + 1] = atomicAdd(&cur[nbi[2 * t + 1]], 1);
        } else if (t < NV + NB) {
            int x = t - NV;
            #pragma unroll
            for (int sl = 0; sl < 2; ++sl)
                posb[BF_BOND + x * 2 + sl] = atomicAdd(&cur[bidx[2 * x + sl]], 1);
        } else if (t < NV + NB + NA) {
            int x = t - (NV + NB);
            #pragma unroll
            for (int sl = 0; sl < 3; ++sl)
                posb[BF_ANGLE + x * 3 + sl] = atomicAdd(&cur[aidx[3 * x + sl]], 1);
        } else if (t < NV + NB + NA + NT) {
            int x = t - (NV + NB + NA);
            #pragma unroll
            for (int sl = 0; sl < 4; ++sl)
                posb[BF_TORS + x * 4 + sl] = atomicAdd(&cur[tidx[4 * x + sl]], 1);
        } else {
            int x = t - (NV + NB + NA + NT);
            #pragma unroll
            for (int sl = 0; sl < 4; ++sl)
                posb[BF_IMP + x * 4 + sl] = atomicAdd(&cur[iidx[4 * x + sl]], 1);
        }
    }
}

// ---------------------------------------------------------------------------
// K5: phaseA — one thread per v, all 16 samples. Coalesced dlv/lv reads,
// energies out, force products packed f16 -> two full 96B entry slots.
// c layout per entry: [comp][s] f16 -> word w = comp*8 + s/2 (lo=even s).
__global__ __launch_bounds__(256, 4) void phaseA_kernel(
    const float* __restrict__ lv, const float* __restrict__ dlv,
    const float4* __restrict__ ws, const int* __restrict__ posv,
    unsigned* __restrict__ c, float* __restrict__ out)
{
    int v = blockIdx.x * 256 + threadIdx.x;
    if (v >= NV) return;
    float4 w = ws[v];
    int p0 = posv[2 * v], p1 = posv[2 * v + 1];
    unsigned cp[48];
    float hold[6];
    #pragma unroll
    for (int s = 0; s < 16; ++s) {
        float r = lv[(size_t)s * NV + v];
        const float2* d2 = (const float2*)(dlv + ((size_t)s * NV + v) * 6);
        float2 dA = d2[0], dB = d2[1], dC = d2[2];
        float rinv = __builtin_amdgcn_rcpf(r);
        float r2inv = rinv * rinv;
        float r6inv = r2inv * r2inv * r2inv;
        float t = w.x * r6inv;
        out[(size_t)s * OUT_S + OFF_EV + v] = w.y * (t * t - 2.0f * t);
        out[(size_t)s * OUT_S + OFF_EC + v] = w.z * rinv;
        float fsv = 12.0f * w.y * t * (1.0f - t) * rinv - w.z * r2inv;
        float c0 = dA.x * fsv, c1 = dA.y * fsv, c2 = dB.x * fsv;
        float c3 = dB.y * fsv, c4 = dC.x * fsv, c5 = dC.y * fsv;
        if ((s & 1) == 0) {
            hold[0] = c0; hold[1] = c1; hold[2] = c2;
            hold[3] = c3; hold[4] = c4; hold[5] = c5;
        } else {
            int sp = s >> 1;
            cp[0 * 8 + sp]      = pkrtz(hold[0], c0);
            cp[1 * 8 + sp]      = pkrtz(hold[1], c1);
            cp[2 * 8 + sp]      = pkrtz(hold[2], c2);
            cp[24 + 0 * 8 + sp] = pkrtz(hold[3], c3);
            cp[24 + 1 * 8 + sp] = pkrtz(hold[4], c4);
            cp[24 + 2 * 8 + sp] = pkrtz(hold[5], c5);
        }
    }
    uint4* dst0 = (uint4*)(c + (size_t)p0 * 24);
    uint4* dst1 = (uint4*)(c + (size_t)p1 * 24);
    #pragma unroll
    for (int k = 0; k < 6; ++k)
        dst0[k] = make_uint4(cp[4 * k], cp[4 * k + 1], cp[4 * k + 2], cp[4 * k + 3]);
    #pragma unroll
    for (int k = 0; k < 6; ++k)
        dst1[k] = make_uint4(cp[24 + 4 * k], cp[24 + 4 * k + 1], cp[24 + 4 * k + 2], cp[24 + 4 * k + 3]);
}

// ---------------------------------------------------------------------------
// K6: bonded — one thread per term, all 16 samples; energies + f16 slots.
__global__ __launch_bounds__(256, 2) void bondedc_kernel(
    const float* __restrict__ lb, const float* __restrict__ th,
    const float* __restrict__ sc, const float* __restrict__ c2i,
    const float* __restrict__ pb, const float* __restrict__ pa,
    const float* __restrict__ pt, const float* __restrict__ pim,
    const float* __restrict__ dlb, const float* __restrict__ dth,
    const float* __restrict__ dtt, const float* __restrict__ dc2,
    const int* __restrict__ posb,
    unsigned* __restrict__ c, float* __restrict__ out)
{
    int t = blockIdx.x * 256 + threadIdx.x;
    if (t >= NBOND_TOT) return;

    if (t < NB) {
        int b = t;
        float2 p = ((const float2*)pb)[b];
        float K = p.x * 100.0f;
        unsigned cp[48]; float hold[6];
        #pragma unroll
        for (int s = 0; s < 16; ++s) {
            float d = lb[s * NB + b] - p.y;
            out[(size_t)s * OUT_S + OFF_EB + b] = K * d * d;
            float g = 2.0f * K * d;
            const float2* dd = (const float2*)(dlb + ((size_t)s * NB + b) * 6);
            float2 dA = dd[0], dB = dd[1], dC = dd[2];
            float v0 = dA.x * g, v1 = dA.y * g, v2 = dB.x * g;
            float v3 = dB.y * g, v4 = dC.x * g, v5 = dC.y * g;
            if ((s & 1) == 0) { hold[0]=v0; hold[1]=v1; hold[2]=v2; hold[3]=v3; hold[4]=v4; hold[5]=v5; }
            else {
                int sp = s >> 1;
                cp[sp]=pkrtz(hold[0],v0); cp[8+sp]=pkrtz(hold[1],v1); cp[16+sp]=pkrtz(hold[2],v2);
                cp[24+sp]=pkrtz(hold[3],v3); cp[32+sp]=pkrtz(hold[4],v4); cp[40+sp]=pkrtz(hold[5],v5);
            }
        }
        #pragma unroll
        for (int sl = 0; sl < 2; ++sl) {
            uint4* dst = (uint4*)(c + (size_t)posb[BF_BOND + b * 2 + sl] * 24);
            #pragma unroll
            for (int k = 0; k < 6; ++k)
                dst[k] = make_uint4(cp[sl*24+4*k], cp[sl*24+4*k+1], cp[sl*24+4*k+2], cp[sl*24+4*k+3]);
        }
    } else if (t < NB + NA) {
        int a = t - NB;
        float2 p = ((const float2*)pa)[a];
        float Ka = p.x * 10.0f;
        float th0 = p.y * 0.31415926535f;
        unsigned cp[72]; float hold[9];
        #pragma unroll
        for (int s = 0; s < 16; ++s) {
            float da = th[s * NA + a] - th0;
            out[(size_t)s * OUT_S + OFF_EA + a] = Ka * da * da;
            float g = 2.0f * Ka * da;
            const float* dd = dth + ((size_t)s * NA + a) * 9;
            float v[9];
            #pragma unroll
            for (int k = 0; k < 9; ++k) v[k] = dd[k] * g;
            if ((s & 1) == 0) {
                #pragma unroll
                for (int k = 0; k < 9; ++k) hold[k] = v[k];
            } else {
                int sp = s >> 1;
                #pragma unroll
                for (int k = 0; k < 9; ++k) cp[k * 8 + sp] = pkrtz(hold[k], v[k]);
            }
        }
        #pragma unroll
        for (int sl = 0; sl < 3; ++sl) {
            uint4* dst = (uint4*)(c + (size_t)posb[BF_ANGLE + a * 3 + sl] * 24);
            #pragma unroll
            for (int k = 0; k < 6; ++k)
                dst[k] = make_uint4(cp[sl*24+4*k], cp[sl*24+4*k+1], cp[sl*24+4*k+2], cp[sl*24+4*k+3]);
        }
    } else if (t < NB + NA + NT) {
        int tt = t - (NB + NA);
        float4 p4 = ((const float4*)pt)[tt];
        unsigned cp[96]; float hold[12];
        #pragma unroll
        for (int s = 0; s < 16; ++s) {
            const float4* s8 = (const float4*)(sc + ((size_t)s * NT + tt) * 8);
            float4 sA = s8[0], sB = s8[1];
            out[(size_t)s * OUT_S + OFF_ET + tt] =
                sA.y * p4.x + sA.w * p4.y + sB.y * p4.z + sB.w * p4.w;
            float g = -(sA.x * p4.x + sA.z * p4.y * 2.0f + sB.x * p4.z * 3.0f + sB.z * p4.w * 4.0f);
            const float4* dd = (const float4*)(dtt + ((size_t)s * NT + tt) * 12);
            float4 dA = dd[0], dB = dd[1], dC = dd[2];
            float v[12] = {dA.x*g, dA.y*g, dA.z*g, dA.w*g, dB.x*g, dB.y*g,
                           dB.z*g, dB.w*g, dC.x*g, dC.y*g, dC.z*g, dC.w*g};
            if ((s & 1) == 0) {
                #pragma unroll
                for (int k = 0; k < 12; ++k) hold[k] = v[k];
            } else {
                int sp = s >> 1;
                #pragma unroll
                for (int k = 0; k < 12; ++k) cp[k * 8 + sp] = pkrtz(hold[k], v[k]);
            }
        }
        #pragma unroll
        for (int sl = 0; sl < 4; ++sl) {
            uint4* dst = (uint4*)(c + (size_t)posb[BF_TORS + tt * 4 + sl] * 24);
            #pragma unroll
            for (int k = 0; k < 6; ++k)
                dst[k] = make_uint4(cp[sl*24+4*k], cp[sl*24+4*k+1], cp[sl*24+4*k+2], cp[sl*24+4*k+3]);
        }
    } else {
        int ii = t - (NB + NA + NT);
        float ki = pim[ii];
        float g = -ki;
        unsigned cp[96]; float hold[12];
        #pragma unroll
        for (int s = 0; s < 16; ++s) {
            out[(size_t)s * OUT_S + OFF_EI + ii] = ki * (1.0f - c2i[s * NI + ii]);
            const float4* dd = (const float4*)(dc2 + ((size_t)s * NI + ii) * 12);
            float4 dA = dd[0], dB = dd[1], dC = dd[2];
            float v[12] = {dA.x*g, dA.y*g, dA.z*g, dA.w*g, dB.x*g, dB.y*g,
                           dB.z*g, dB.w*g, dC.x*g, dC.y*g, dC.z*g, dC.w*g};
            if ((s & 1) == 0) {
                #pragma unroll
                for (int k = 0; k < 12; ++k) hold[k] = v[k];
            } else {
                int sp = s >> 1;
                #pragma unroll
                for (int k = 0; k < 12; ++k) cp[k * 8 + sp] = pkrtz(hold[k], v[k]);
            }
        }
        #pragma unroll
        for (int sl = 0; sl < 4; ++sl) {
            uint4* dst = (uint4*)(c + (size_t)posb[BF_IMP + ii * 4 + sl] * 24);
            #pragma unroll
            for (int k = 0; k < 6; ++k)
                dst[k] = make_uint4(cp[sl*24+4*k], cp[sl*24+4*k+1], cp[sl*24+4*k+2], cp[sl*24+4*k+3]);
        }
    }
}

// ---------------------------------------------------------------------------
// K7: gather — wave per atom; contributions are CONTIGUOUS. Coalesced 96B
// reads, packed f16 adds, shuffle reduce, coalesced F write. Zero atomics.
__global__ __launch_bounds__(256, 2) void gather_kernel(
    const unsigned* __restrict__ c, const int* __restrict__ startx,
    float* __restrict__ out)
{
    __shared__ float red[4][48];
    int wv = threadIdx.x >> 6, lane = threadIdx.x & 63;
    int a0 = blockIdx.x * 4;
    int a = a0 + wv;
    int base = startx[a], endp = startx[a + 1];

    unsigned acc[24];
    #pragma unroll
    for (int k = 0; k < 24; ++k) acc[k] = 0u;

    for (int i = base + lane; i < endp; i += 64) {
        const uint4* e = (const uint4*)(c + (size_t)i * 24);
        uint4 q0 = e[0], q1 = e[1], q2 = e[2], q3 = e[3], q4 = e[4], q5 = e[5];
        acc[0]  = hadd2u(acc[0],  q0.x); acc[1]  = hadd2u(acc[1],  q0.y);
        acc[2]  = hadd2u(acc[2],  q0.z); acc[3]  = hadd2u(acc[3],  q0.w);
        acc[4]  = hadd2u(acc[4],  q1.x); acc[5]  = hadd2u(acc[5],  q1.y);
        acc[6]  = hadd2u(acc[6],  q1.z); acc[7]  = hadd2u(acc[7],  q1.w);
        acc[8]  = hadd2u(acc[8],  q2.x); acc[9]  = hadd2u(acc[9],  q2.y);
        acc[10] = hadd2u(acc[10], q2.z); acc[11] = hadd2u(acc[11], q2.w);
        acc[12] = hadd2u(acc[12], q3.x); acc[13] = hadd2u(acc[13], q3.y);
        acc[14] = hadd2u(acc[14], q3.z); acc[15] = hadd2u(acc[15], q3.w);
        acc[16] = hadd2u(acc[16], q4.x); acc[17] = hadd2u(acc[17], q4.y);
        acc[18] = hadd2u(acc[18], q4.z); acc[19] = hadd2u(acc[19], q4.w);
        acc[20] = hadd2u(acc[20], q5.x); acc[21] = hadd2u(acc[21], q5.y);
        acc[22] = hadd2u(acc[22], q5.z); acc[23] = hadd2u(acc[23], q5.w);
    }
    #pragma unroll
    for (int off = 32; off > 0; off >>= 1) {
        #pragma unroll
        for (int k = 0; k < 24; ++k) {
            unsigned o = __shfl_down(acc[k], off);
            acc[k] = hadd2u(acc[k], o);
        }
    }
    if (lane == 0) {
        #pragma unroll
        for (int w = 0; w < 24; ++w) {
            __half2 h = __builtin_bit_cast(__half2, acc[w]);
            int comp = w >> 3, sp = w & 7;
            red[wv][comp * 16 + 2 * sp]     = __low2float(h);
            red[wv][comp * 16 + 2 * sp + 1] = __high2float(h);
        }
    }
    __syncthreads();
    int th = threadIdx.x;
    if (th < 192) {
        int s = th / 12, idx = th % 12;
        int ai = idx / 3, comp = idx % 3;
        out[(size_t)s * OUT_S + OFF_F + 3 * (a0 + ai) + comp] = red[ai][comp * 16 + s];
    }
}

// ---------------------------------------------------------------------------
extern "C" void kernel_launch(void* const* d_in, const int* in_sizes, int n_in,
                              void* d_out, int out_size, void* d_ws, size_t ws_size,
                              hipStream_t stream) {
    const float* lb  = (const float*)d_in[0];
    const float* th  = (const float*)d_in[1];
    const float* lv  = (const float*)d_in[2];
    const float* sc  = (const float*)d_in[3];
    const float* c2i = (const float*)d_in[4];
    const float* v14 = (const float*)d_in[5];
    const float* q14 = (const float*)d_in[6];
    const float* pb  = (const float*)d_in[7];
    const float* pa  = (const float*)d_in[8];
    const float* pv  = (const float*)d_in[9];
    const float* pc  = (const float*)d_in[10];
    const float* pt  = (const float*)d_in[11];
    const float* pim = (const float*)d_in[12];
    const float* dlb = (const float*)d_in[13];
    const float* dth = (const float*)d_in[14];
    const float* dlv = (const float*)d_in[15];
    const float* dtt = (const float*)d_in[16];
    const float* dc2 = (const float*)d_in[17];
    const int* nb    = (const int*)d_in[18];
    const int* bidx  = (const int*)d_in[19];
    const int* aidx  = (const int*)d_in[20];
    const int* nbi   = (const int*)d_in[21];
    const int* tidx  = (const int*)d_in[22];
    const int* iidx  = (const int*)d_in[23];
    float* out = (float*)d_out;

    // ws layout: c (16B-aligned, first) | params | posv | posb | counts | total | startx
    unsigned* c      = (unsigned*)d_ws;                       // NENT*24 u32 = 81MB
    float4*   ws     = (float4*)(c + (size_t)NENT * 24);      // NV
    int*      posv   = (int*)(ws + NV);                       // 2*NV
    int*      posb   = posv + 2 * NV;                         // NBF
    int*      counts = posb + NBF;                            // NCB*N_ATOMS
    int*      total  = counts + (size_t)NCB * N_ATOMS;        // N_ATOMS
    int*      startx = total + N_ATOMS;                       // N_ATOMS+1

    init_kernel<<<(NV + 511) / 512, 512, 0, stream>>>(v14, q14, pv, pc, nb, ws, out);
    hist_kernel<<<NCB, 256, 0, stream>>>(nbi, bidx, aidx, tidx, iidx, counts);
    colscan_kernel<<<(N_ATOMS + 255) / 256, 256, 0, stream>>>(counts, total);
    scan_kernel<<<1, 64, 0, stream>>>(total, startx);
    place_kernel<<<NCB, 256, 0, stream>>>(nbi, bidx, aidx, tidx, iidx, counts, startx, posv, posb);
    phaseA_kernel<<<(NV + 255) / 256, 256, 0, stream>>>(lv, dlv, ws, posv, c, out);
    bondedc_kernel<<<(NBOND_TOT + 255) / 256, 256, 0, stream>>>(
        lb, th, sc, c2i, pb, pa, pt, pim, dlb, dth, dtt, dc2, posb, c, out);
    gather_kernel<<<N_ATOMS / 4, 256, 0, stream>>>(c, startx, out);
}

// Round 12
// 171.968 us; speedup vs baseline: 3.5933x; 1.0034x over previous
//
#include <hip/hip_runtime.h>
#include <hip/hip_fp16.h>

#define NS 16
#define N_ATOMS 2000
#define NB 2000
#define NA 4000
#define NV 400000
#define NT 6000
#define NI 1000

#define OUT_S 819001
#define OFF_EB 0
#define OFF_EA 2000
#define OFF_EUB 6000
#define OFF_EV 6001
#define OFF_EC 406001
#define OFF_ET 806001
#define OFF_EI 812001
#define OFF_F 813001

#define CHARGE_TENTH 1.8222615f

#define NBF 44000            // bonded slots: 2000*2 + 4000*3 + 6000*4 + 1000*4
#define BF_BOND 0
#define BF_ANGLE 4000
#define BF_TORS 16000
#define BF_IMP 40000
#define NENT (NV * 2 + NBF)  // 844000 entries
#define NBOND_TOT (NB + NA + NT + NI)   // 13000
#define NITEMS (NV + NB + NA + NT + NI) // 413000
#define NCB 256
#define IPB ((NITEMS + NCB - 1) / NCB)  // 1614

// c-entry layout (24 u32 = 96B): word w = h*12 + comp*4 + q
//   h = sample-half (0: s=0..7, 1: s=8..15), comp = x/y/z, q: samples (h*8+2q, h*8+2q+1) lo/hi.

typedef __fp16 hv2 __attribute__((ext_vector_type(2)));

__device__ __forceinline__ unsigned pkrtz(float a, float b) {
    hv2 h = __builtin_amdgcn_cvt_pkrtz(a, b);
    return __builtin_bit_cast(unsigned, h);
}
__device__ __forceinline__ unsigned hadd2u(unsigned x, unsigned y) {
    __half2 a = __builtin_bit_cast(__half2, x);
    __half2 b = __builtin_bit_cast(__half2, y);
    return __builtin_bit_cast(unsigned, __hadd2(a, b));
}

// ---------------------------------------------------------------------------
// K1: E_ub zero + per-v vdw/charge params.
__global__ __launch_bounds__(512) void init_kernel(
    const float* __restrict__ v14, const float* __restrict__ q14,
    const float* __restrict__ pv, const float* __restrict__ pc,
    const int* __restrict__ nb, float4* __restrict__ ws, float* __restrict__ out)
{
    int idx = blockIdx.x * blockDim.x + threadIdx.x;
    if (idx < NS) out[(size_t)idx * OUT_S + OFF_EUB] = 0.0f;
    if (idx < NV) {
        int v = idx;
        int i = nb[v];
        int j = nb[NV + v];
        float2 pvi = ((const float2*)pv)[i];
        float2 pvj = ((const float2*)pv)[j];
        float sigma = pvi.x + pvj.x;
        float sig2 = sigma * sigma;
        float4 w;
        w.x = sig2 * sig2 * sig2;
        w.y = pvi.y * pvj.y * 0.01f * v14[v];
        w.z = (CHARGE_TENTH * CHARGE_TENTH) * pc[i] * pc[j] * q14[v];
        w.w = 0.0f;
        ws[v] = w;
    }
}

// ---------------------------------------------------------------------------
// K2: per-block LDS histogram of contributions per atom.
__global__ __launch_bounds__(256, 4) void hist_kernel(
    const int* __restrict__ nbi, const int* __restrict__ bidx,
    const int* __restrict__ aidx, const int* __restrict__ tidx,
    const int* __restrict__ iidx, int* __restrict__ counts)
{
    __shared__ int h[N_ATOMS];
    int tid = threadIdx.x, b = blockIdx.x;
    for (int k = tid; k < N_ATOMS; k += 256) h[k] = 0;
    __syncthreads();
    int t0 = b * IPB, t1 = t0 + IPB; if (t1 > NITEMS) t1 = NITEMS;
    for (int t = t0 + tid; t < t1; t += 256) {
        if (t < NV) {
            atomicAdd(&h[nbi[2 * t]], 1);
            atomicAdd(&h[nbi[2 * t + 1]], 1);
        } else if (t < NV + NB) {
            int x = t - NV;
            atomicAdd(&h[bidx[2 * x]], 1);
            atomicAdd(&h[bidx[2 * x + 1]], 1);
        } else if (t < NV + NB + NA) {
            int x = t - (NV + NB);
            atomicAdd(&h[aidx[3 * x]], 1);
            atomicAdd(&h[aidx[3 * x + 1]], 1);
            atomicAdd(&h[aidx[3 * x + 2]], 1);
        } else if (t < NV + NB + NA + NT) {
            int x = t - (NV + NB + NA);
            #pragma unroll
            for (int p = 0; p < 4; ++p) atomicAdd(&h[tidx[4 * x + p]], 1);
        } else {
            int x = t - (NV + NB + NA + NT);
            #pragma unroll
            for (int p = 0; p < 4; ++p) atomicAdd(&h[iidx[4 * x + p]], 1);
        }
    }
    __syncthreads();
    for (int k = tid; k < N_ATOMS; k += 256) counts[(size_t)b * N_ATOMS + k] = h[k];
}

// K3a: column scan over blocks.
__global__ __launch_bounds__(256) void colscan_kernel(
    int* __restrict__ counts, int* __restrict__ total)
{
    int a = blockIdx.x * 256 + threadIdx.x;
    if (a >= N_ATOMS) return;
    int pre = 0;
    for (int b = 0; b < NCB; ++b) {
        int c = counts[(size_t)b * N_ATOMS + a];
        counts[(size_t)b * N_ATOMS + a] = pre;
        pre += c;
    }
    total[a] = pre;
}

// K3b: single-wave exclusive scan over atoms.
__global__ __launch_bounds__(64) void scan_kernel(
    const int* __restrict__ total, int* __restrict__ startx)
{
    int lane = threadIdx.x;
    const int CH = (N_ATOMS + 63) / 64;
    int a0 = lane * CH, a1 = a0 + CH; if (a1 > N_ATOMS) a1 = N_ATOMS;
    int tot = 0;
    for (int a = a0; a < a1; ++a) tot += total[a];
    int incl = tot;
    #pragma unroll
    for (int off = 1; off < 64; off <<= 1) {
        int n = __shfl_up(incl, off);
        if (lane >= off) incl += n;
    }
    int run = incl - tot;
    for (int a = a0; a < a1; ++a) { startx[a] = run; run += total[a]; }
    if (lane == 63) startx[N_ATOMS] = run;
}

// K4: placement — inverse permutation pos[code] = slot.
__global__ __launch_bounds__(256, 4) void place_kernel(
    const int* __restrict__ nbi, const int* __restrict__ bidx,
    const int* __restrict__ aidx, const int* __restrict__ tidx,
    const int* __restrict__ iidx, const int* __restrict__ counts,
    const int* __restrict__ startx,
    int* __restrict__ posv, int* __restrict__ posb)
{
    __shared__ int cur[N_ATOMS];
    int tid = threadIdx.x, b = blockIdx.x;
    for (int k = tid; k < N_ATOMS; k += 256)
        cur[k] = startx[k] + counts[(size_t)b * N_ATOMS + k];
    __syncthreads();
    int t0 = b * IPB, t1 = t0 + IPB; if (t1 > NITEMS) t1 = NITEMS;
    for (int t = t0 + tid; t < t1; t += 256) {
        if (t < NV) {
            posv[2 * t]     = atomicAdd(&cur[nbi[2 * t]], 1);
            posv[2 * t + 1] = atomicAdd(&cur[nbi[2 * t + 1]], 1);
        } else if (t < NV + NB) {
            int x = t - NV;
            #pragma unroll
            for (int sl = 0; sl < 2; ++sl)
                posb[BF_BOND + x * 2 + sl] = atomicAdd(&cur[bidx[2 * x + sl]], 1);
        } else if (t < NV + NB + NA) {
            int x = t - (NV + NB);
            #pragma unroll
            for (int sl = 0; sl < 3; ++sl)
                posb[BF_ANGLE + x * 3 + sl] = atomicAdd(&cur[aidx[3 * x + sl]], 1);
        } else if (t < NV + NB + NA + NT) {
            int x = t - (NV + NB + NA);
            #pragma unroll
            for (int sl = 0; sl < 4; ++sl)
                posb[BF_TORS + x * 4 + sl] = atomicAdd(&cur[tidx[4 * x + sl]], 1);
        } else {
            int x = t - (NV + NB + NA + NT);
            #pragma unroll
            for (int sl = 0; sl < 4; ++sl)
                posb[BF_IMP + x * 4 + sl] = atomicAdd(&cur[iidx[4 * x + sl]], 1);
        }
    }
}

// ---------------------------------------------------------------------------
// K5: phaseA — one thread per (v, sample-half). cp shrinks to 24 words so the
// 8 independent iterations' loads can stay in flight (register headroom).
__global__ __launch_bounds__(256, 4) void phaseA_kernel(
    const float* __restrict__ lv, const float* __restrict__ dlv,
    const float4* __restrict__ ws, const int* __restrict__ posv,
    unsigned* __restrict__ c, float* __restrict__ out)
{
    int v = blockIdx.x * 256 + threadIdx.x;
    if (v >= NV) return;
    int h = blockIdx.y;
    float4 w = ws[v];
    int2 pp = *(const int2*)(posv + 2 * v);
    unsigned cp[24];
    float hold[6];
    #pragma unroll
    for (int j = 0; j < 8; ++j) {
        int s = h * 8 + j;
        float r = lv[(size_t)s * NV + v];
        const float2* d2 = (const float2*)(dlv + ((size_t)s * NV + v) * 6);
        float2 dA = d2[0], dB = d2[1], dC = d2[2];
        float rinv = __builtin_amdgcn_rcpf(r);
        float r2inv = rinv * rinv;
        float r6inv = r2inv * r2inv * r2inv;
        float t = w.x * r6inv;
        out[(size_t)s * OUT_S + OFF_EV + v] = w.y * (t * t - 2.0f * t);
        out[(size_t)s * OUT_S + OFF_EC + v] = w.z * rinv;
        float fsv = 12.0f * w.y * t * (1.0f - t) * rinv - w.z * r2inv;
        float c0 = dA.x * fsv, c1 = dA.y * fsv, c2 = dB.x * fsv;
        float c3 = dB.y * fsv, c4 = dC.x * fsv, c5 = dC.y * fsv;
        if ((j & 1) == 0) {
            hold[0] = c0; hold[1] = c1; hold[2] = c2;
            hold[3] = c3; hold[4] = c4; hold[5] = c5;
        } else {
            int q = j >> 1;
            cp[0 * 4 + q]      = pkrtz(hold[0], c0);
            cp[1 * 4 + q]      = pkrtz(hold[1], c1);
            cp[2 * 4 + q]      = pkrtz(hold[2], c2);
            cp[12 + 0 * 4 + q] = pkrtz(hold[3], c3);
            cp[12 + 1 * 4 + q] = pkrtz(hold[4], c4);
            cp[12 + 2 * 4 + q] = pkrtz(hold[5], c5);
        }
    }
    uint4* dst0 = (uint4*)(c + (size_t)pp.x * 24 + h * 12);
    uint4* dst1 = (uint4*)(c + (size_t)pp.y * 24 + h * 12);
    #pragma unroll
    for (int k = 0; k < 3; ++k)
        dst0[k] = make_uint4(cp[4 * k], cp[4 * k + 1], cp[4 * k + 2], cp[4 * k + 3]);
    #pragma unroll
    for (int k = 0; k < 3; ++k)
        dst1[k] = make_uint4(cp[12 + 4 * k], cp[12 + 4 * k + 1], cp[12 + 4 * k + 2], cp[12 + 4 * k + 3]);
}

// ---------------------------------------------------------------------------
// K6: bonded — one thread per term, all 16 samples; energies + f16 slots.
// cp index per slot sl, sample s: sp=s>>1, h=sp>>2, q=sp&3 ->
//   cp[sl*24 + h*12 + comp*4 + q]
__global__ __launch_bounds__(256, 2) void bondedc_kernel(
    const float* __restrict__ lb, const float* __restrict__ th,
    const float* __restrict__ sc, const float* __restrict__ c2i,
    const float* __restrict__ pb, const float* __restrict__ pa,
    const float* __restrict__ pt, const float* __restrict__ pim,
    const float* __restrict__ dlb, const float* __restrict__ dth,
    const float* __restrict__ dtt, const float* __restrict__ dc2,
    const int* __restrict__ posb,
    unsigned* __restrict__ c, float* __restrict__ out)
{
    int t = blockIdx.x * 256 + threadIdx.x;
    if (t >= NBOND_TOT) return;

    if (t < NB) {
        int b = t;
        float2 p = ((const float2*)pb)[b];
        float K = p.x * 100.0f;
        unsigned cp[48]; float hold[6];
        #pragma unroll
        for (int s = 0; s < 16; ++s) {
            float d = lb[s * NB + b] - p.y;
            out[(size_t)s * OUT_S + OFF_EB + b] = K * d * d;
            float g = 2.0f * K * d;
            const float2* dd = (const float2*)(dlb + ((size_t)s * NB + b) * 6);
            float2 dA = dd[0], dB = dd[1], dC = dd[2];
            float v0 = dA.x * g, v1 = dA.y * g, v2 = dB.x * g;
            float v3 = dB.y * g, v4 = dC.x * g, v5 = dC.y * g;
            if ((s & 1) == 0) { hold[0]=v0; hold[1]=v1; hold[2]=v2; hold[3]=v3; hold[4]=v4; hold[5]=v5; }
            else {
                int sp = s >> 1, h = sp >> 2, q = sp & 3;
                cp[0*24 + h*12 + 0*4 + q] = pkrtz(hold[0], v0);
                cp[0*24 + h*12 + 1*4 + q] = pkrtz(hold[1], v1);
                cp[0*24 + h*12 + 2*4 + q] = pkrtz(hold[2], v2);
                cp[1*24 + h*12 + 0*4 + q] = pkrtz(hold[3], v3);
                cp[1*24 + h*12 + 1*4 + q] = pkrtz(hold[4], v4);
                cp[1*24 + h*12 + 2*4 + q] = pkrtz(hold[5], v5);
            }
        }
        #pragma unroll
        for (int sl = 0; sl < 2; ++sl) {
            uint4* dst = (uint4*)(c + (size_t)posb[BF_BOND + b * 2 + sl] * 24);
            #pragma unroll
            for (int k = 0; k < 6; ++k)
                dst[k] = make_uint4(cp[sl*24+4*k], cp[sl*24+4*k+1], cp[sl*24+4*k+2], cp[sl*24+4*k+3]);
        }
    } else if (t < NB + NA) {
        int a = t - NB;
        float2 p = ((const float2*)pa)[a];
        float Ka = p.x * 10.0f;
        float th0 = p.y * 0.31415926535f;
        unsigned cp[72]; float hold[9];
        #pragma unroll
        for (int s = 0; s < 16; ++s) {
            float da = th[s * NA + a] - th0;
            out[(size_t)s * OUT_S + OFF_EA + a] = Ka * da * da;
            float g = 2.0f * Ka * da;
            const float* dd = dth + ((size_t)s * NA + a) * 9;
            float v[9];
            #pragma unroll
            for (int k = 0; k < 9; ++k) v[k] = dd[k] * g;
            if ((s & 1) == 0) {
                #pragma unroll
                for (int k = 0; k < 9; ++k) hold[k] = v[k];
            } else {
                int sp = s >> 1, h = sp >> 2, q = sp & 3;
                #pragma unroll
                for (int k = 0; k < 9; ++k)
                    cp[(k / 3) * 24 + h * 12 + (k % 3) * 4 + q] = pkrtz(hold[k], v[k]);
            }
        }
        #pragma unroll
        for (int sl = 0; sl < 3; ++sl) {
            uint4* dst = (uint4*)(c + (size_t)posb[BF_ANGLE + a * 3 + sl] * 24);
            #pragma unroll
            for (int k = 0; k < 6; ++k)
                dst[k] = make_uint4(cp[sl*24+4*k], cp[sl*24+4*k+1], cp[sl*24+4*k+2], cp[sl*24+4*k+3]);
        }
    } else if (t < NB + NA + NT) {
        int tt = t - (NB + NA);
        float4 p4 = ((const float4*)pt)[tt];
        unsigned cp[96]; float hold[12];
        #pragma unroll
        for (int s = 0; s < 16; ++s) {
            const float4* s8 = (const float4*)(sc + ((size_t)s * NT + tt) * 8);
            float4 sA = s8[0], sB = s8[1];
            out[(size_t)s * OUT_S + OFF_ET + tt] =
                sA.y * p4.x + sA.w * p4.y + sB.y * p4.z + sB.w * p4.w;
            float g = -(sA.x * p4.x + sA.z * p4.y * 2.0f + sB.x * p4.z * 3.0f + sB.z * p4.w * 4.0f);
            const float4* dd = (const float4*)(dtt + ((size_t)s * NT + tt) * 12);
            float4 dA = dd[0], dB = dd[1], dC = dd[2];
            float v[12] = {dA.x*g, dA.y*g, dA.z*g, dA.w*g, dB.x*g, dB.y*g,
                           dB.z*g, dB.w*g, dC.x*g, dC.y*g, dC.z*g, dC.w*g};
            if ((s & 1) == 0) {
                #pragma unroll
                for (int k = 0; k < 12; ++k) hold[k] = v[k];
            } else {
                int sp = s >> 1, h = sp >> 2, q = sp & 3;
                #pragma unroll
                for (int k = 0; k < 12; ++k)
                    cp[(k / 3) * 24 + h * 12 + (k % 3) * 4 + q] = pkrtz(hold[k], v[k]);
            }
        }
        #pragma unroll
        for (int sl = 0; sl < 4; ++sl) {
            uint4* dst = (uint4*)(c + (size_t)posb[BF_TORS + tt * 4 + sl] * 24);
            #pragma unroll
            for (int k = 0; k < 6; ++k)
                dst[k] = make_uint4(cp[sl*24+4*k], cp[sl*24+4*k+1], cp[sl*24+4*k+2], cp[sl*24+4*k+3]);
        }
    } else {
        int ii = t - (NB + NA + NT);
        float ki = pim[ii];
        float g = -ki;
        unsigned cp[96]; float hold[12];
        #pragma unroll
        for (int s = 0; s < 16; ++s) {
            out[(size_t)s * OUT_S + OFF_EI + ii] = ki * (1.0f - c2i[s * NI + ii]);
            const float4* dd = (const float4*)(dc2 + ((size_t)s * NI + ii) * 12);
            float4 dA = dd[0], dB = dd[1], dC = dd[2];
            float v[12] = {dA.x*g, dA.y*g, dA.z*g, dA.w*g, dB.x*g, dB.y*g,
                           dB.z*g, dB.w*g, dC.x*g, dC.y*g, dC.z*g, dC.w*g};
            if ((s & 1) == 0) {
                #pragma unroll
                for (int k = 0; k < 12; ++k) hold[k] = v[k];
            } else {
                int sp = s >> 1, h = sp >> 2, q = sp & 3;
                #pragma unroll
                for (int k = 0; k < 12; ++k)
                    cp[(k / 3) * 24 + h * 12 + (k % 3) * 4 + q] = pkrtz(hold[k], v[k]);
            }
        }
        #pragma unroll
        for (int sl = 0; sl < 4; ++sl) {
            uint4* dst = (uint4*)(c + (size_t)posb[BF_IMP + ii * 4 + sl] * 24);
            #pragma unroll
            for (int k = 0; k < 6; ++k)
                dst[k] = make_uint4(cp[sl*24+4*k], cp[sl*24+4*k+1], cp[sl*24+4*k+2], cp[sl*24+4*k+3]);
        }
    }
}

// ---------------------------------------------------------------------------
// K7: gather — wave per atom; contributions contiguous; packed f16 adds.
__global__ __launch_bounds__(256, 2) void gather_kernel(
    const unsigned* __restrict__ c, const int* __restrict__ startx,
    float* __restrict__ out)
{
    __shared__ float red[4][48];
    int wv = threadIdx.x >> 6, lane = threadIdx.x & 63;
    int a0 = blockIdx.x * 4;
    int a = a0 + wv;
    int base = startx[a], endp = startx[a + 1];

    unsigned acc[24];
    #pragma unroll
    for (int k = 0; k < 24; ++k) acc[k] = 0u;

    for (int i = base + lane; i < endp; i += 64) {
        const uint4* e = (const uint4*)(c + (size_t)i * 24);
        uint4 q0 = e[0], q1 = e[1], q2 = e[2], q3 = e[3], q4 = e[4], q5 = e[5];
        acc[0]  = hadd2u(acc[0],  q0.x); acc[1]  = hadd2u(acc[1],  q0.y);
        acc[2]  = hadd2u(acc[2],  q0.z); acc[3]  = hadd2u(acc[3],  q0.w);
        acc[4]  = hadd2u(acc[4],  q1.x); acc[5]  = hadd2u(acc[5],  q1.y);
        acc[6]  = hadd2u(acc[6],  q1.z); acc[7]  = hadd2u(acc[7],  q1.w);
        acc[8]  = hadd2u(acc[8],  q2.x); acc[9]  = hadd2u(acc[9],  q2.y);
        acc[10] = hadd2u(acc[10], q2.z); acc[11] = hadd2u(acc[11], q2.w);
        acc[12] = hadd2u(acc[12], q3.x); acc[13] = hadd2u(acc[13], q3.y);
        acc[14] = hadd2u(acc[14], q3.z); acc[15] = hadd2u(acc[15], q3.w);
        acc[16] = hadd2u(acc[16], q4.x); acc[17] = hadd2u(acc[17], q4.y);
        acc[18] = hadd2u(acc[18], q4.z); acc[19] = hadd2u(acc[19], q4.w);
        acc[20] = hadd2u(acc[20], q5.x); acc[21] = hadd2u(acc[21], q5.y);
        acc[22] = hadd2u(acc[22], q5.z); acc[23] = hadd2u(acc[23], q5.w);
    }
    #pragma unroll
    for (int off = 32; off > 0; off >>= 1) {
        #pragma unroll
        for (int k = 0; k < 24; ++k) {
            unsigned o = __shfl_down(acc[k], off);
            acc[k] = hadd2u(acc[k], o);
        }
    }
    if (lane == 0) {
        #pragma unroll
        for (int w = 0; w < 24; ++w) {
            __half2 hh = __builtin_bit_cast(__half2, acc[w]);
            int h = (w >= 12) ? 1 : 0;
            int rem = w - h * 12;
            int comp = rem >> 2, q = rem & 3;
            int s0 = h * 8 + 2 * q;
            red[wv][comp * 16 + s0]     = __low2float(hh);
            red[wv][comp * 16 + s0 + 1] = __high2float(hh);
        }
    }
    __syncthreads();
    int th = threadIdx.x;
    if (th < 192) {
        int s = th / 12, idx = th % 12;
        int ai = idx / 3, comp = idx % 3;
        out[(size_t)s * OUT_S + OFF_F + 3 * (a0 + ai) + comp] = red[ai][comp * 16 + s];
    }
}

// ---------------------------------------------------------------------------
extern "C" void kernel_launch(void* const* d_in, const int* in_sizes, int n_in,
                              void* d_out, int out_size, void* d_ws, size_t ws_size,
                              hipStream_t stream) {
    const float* lb  = (const float*)d_in[0];
    const float* th  = (const float*)d_in[1];
    const float* lv  = (const float*)d_in[2];
    const float* sc  = (const float*)d_in[3];
    const float* c2i = (const float*)d_in[4];
    const float* v14 = (const float*)d_in[5];
    const float* q14 = (const float*)d_in[6];
    const float* pb  = (const float*)d_in[7];
    const float* pa  = (const float*)d_in[8];
    const float* pv  = (const float*)d_in[9];
    const float* pc  = (const float*)d_in[10];
    const float* pt  = (const float*)d_in[11];
    const float* pim = (const float*)d_in[12];
    const float* dlb = (const float*)d_in[13];
    const float* dth = (const float*)d_in[14];
    const float* dlv = (const float*)d_in[15];
    const float* dtt = (const float*)d_in[16];
    const float* dc2 = (const float*)d_in[17];
    const int* nb    = (const int*)d_in[18];
    const int* bidx  = (const int*)d_in[19];
    const int* aidx  = (const int*)d_in[20];
    const int* nbi   = (const int*)d_in[21];
    const int* tidx  = (const int*)d_in[22];
    const int* iidx  = (const int*)d_in[23];
    float* out = (float*)d_out;

    // ws layout: c | params | posv | posb | counts | total | startx
    unsigned* c      = (unsigned*)d_ws;                       // NENT*24 u32
    float4*   ws     = (float4*)(c + (size_t)NENT * 24);      // NV
    int*      posv   = (int*)(ws + NV);                       // 2*NV
    int*      posb   = posv + 2 * NV;                         // NBF
    int*      counts = posb + NBF;                            // NCB*N_ATOMS
    int*      total  = counts + (size_t)NCB * N_ATOMS;        // N_ATOMS
    int*      startx = total + N_ATOMS;                       // N_ATOMS+1

    init_kernel<<<(NV + 511) / 512, 512, 0, stream>>>(v14, q14, pv, pc, nb, ws, out);
    hist_kernel<<<NCB, 256, 0, stream>>>(nbi, bidx, aidx, tidx, iidx, counts);
    colscan_kernel<<<(N_ATOMS + 255) / 256, 256, 0, stream>>>(counts, total);
    scan_kernel<<<1, 64, 0, stream>>>(total, startx);
    place_kernel<<<NCB, 256, 0, stream>>>(nbi, bidx, aidx, tidx, iidx, counts, startx, posv, posb);
    {
        dim3 grid((NV + 255) / 256, 2);
        phaseA_kernel<<<grid, 256, 0, stream>>>(lv, dlv, ws, posv, c, out);
    }
    bondedc_kernel<<<(NBOND_TOT + 255) / 256, 256, 0, stream>>>(
        lb, th, sc, c2i, pb, pa, pt, pim, dlb, dth, dtt, dc2, posb, c, out);
    gather_kernel<<<N_ATOMS / 4, 256, 0, stream>>>(c, startx, out);
}